// Round 1
// baseline (117.488 us; speedup 1.0000x reference)
//
#include <hip/hip_runtime.h>

// Radius search (L2^2), fixed single segment.
// Outputs concatenated as float32:
//   [0, MN)            neighbors_index  (packed, pad -1)
//   [MN, MN+M+1)       neighbors_row_splits
//   [MN+M+1, 2MN+M+1)  neighbors_distance (packed, pad 0)
//
// Numerics must match numpy float32 exactly (packing shifts otherwise):
//   q2 = (qx*qx + qy*qy) + qz*qz   (per-op round, NO fma)
//   p2 = (px*px + py*py) + pz*pz
//   qp = (qx*px + qy*py) + qz*pz
//   d2 = max((q2 + p2) - 2*qp, 0)
//   mask: d2 <= r*r

__device__ __forceinline__ float d2_exact(float qx, float qy, float qz,
                                          float px, float py, float pz) {
    float q2 = __fadd_rn(__fadd_rn(__fmul_rn(qx, qx), __fmul_rn(qy, qy)), __fmul_rn(qz, qz));
    float p2 = __fadd_rn(__fadd_rn(__fmul_rn(px, px), __fmul_rn(py, py)), __fmul_rn(pz, pz));
    float qp = __fadd_rn(__fadd_rn(__fmul_rn(qx, px), __fmul_rn(qy, py)), __fmul_rn(qz, pz));
    float d2 = __fsub_rn(__fadd_rn(q2, p2), __fmul_rn(2.0f, qp));
    return fmaxf(d2, 0.0f);
}

// One wave (64 lanes) per query: count neighbors.
__global__ void rs_count(const float* __restrict__ points,
                         const float* __restrict__ queries,
                         const float* __restrict__ radii,
                         int* __restrict__ counts, int N, int M) {
    int wid = (int)((blockIdx.x * blockDim.x + threadIdx.x) >> 6);
    int lane = threadIdx.x & 63;
    if (wid >= M) return;
    float qx = queries[3 * wid + 0];
    float qy = queries[3 * wid + 1];
    float qz = queries[3 * wid + 2];
    float r = radii[wid];
    float r2 = __fmul_rn(r, r);
    int cnt = 0;
    for (int p = lane; p < N; p += 64) {
        float px = points[3 * p + 0];
        float py = points[3 * p + 1];
        float pz = points[3 * p + 2];
        float d2 = d2_exact(qx, qy, qz, px, py, pz);
        cnt += (d2 <= r2) ? 1 : 0;
    }
    for (int off = 32; off > 0; off >>= 1) cnt += __shfl_down(cnt, off, 64);
    if (lane == 0) counts[wid] = cnt;
}

// Single block of 256 threads: exclusive scan of counts[M] -> splits (int32 ws + float out).
__global__ void rs_scan(const int* __restrict__ counts,
                        int* __restrict__ splits_i,
                        float* __restrict__ splits_f, int M) {
    __shared__ int lds[256];
    int t = threadIdx.x;
    int per = M / 256;  // M divisible by 256 (4096)
    int local[64];      // per <= 64 supported
    int sum = 0;
    for (int i = 0; i < per; ++i) {
        int c = counts[t * per + i];
        local[i] = sum;
        sum += c;
    }
    lds[t] = sum;
    __syncthreads();
    for (int off = 1; off < 256; off <<= 1) {
        int add = (t >= off) ? lds[t - off] : 0;
        __syncthreads();
        lds[t] += add;
        __syncthreads();
    }
    int excl = (t == 0) ? 0 : lds[t - 1];
    for (int i = 0; i < per; ++i) {
        int v = excl + local[i];
        splits_i[t * per + i] = v;
        splits_f[t * per + i] = (float)v;
    }
    if (t == 255) {
        int total = excl + sum;
        splits_i[M] = total;
        splits_f[M] = (float)total;
    }
}

// Grid-stride fill of out[start,end) with val, float4 body.
__global__ void rs_fill(float* __restrict__ out, long long start, long long end, float val) {
    long long n = end - start;
    float* base = out + start;
    long long head = (long long)(((16u - ((unsigned)(size_t)base & 15u)) & 15u) >> 2);
    if (head > n) head = n;
    long long tid = (long long)blockIdx.x * blockDim.x + threadIdx.x;
    long long nth = (long long)gridDim.x * blockDim.x;
    for (long long i = tid; i < head; i += nth) base[i] = val;
    long long nv = (n - head) >> 2;
    float4* v = (float4*)(base + head);
    float4 vv = make_float4(val, val, val, val);
    for (long long i = tid; i < nv; i += nth) v[i] = vv;
    for (long long i = head + (nv << 2) + tid; i < n; i += nth) base[i] = val;
}

// One wave per query: recompute d2, pack indices+distances in point-index order.
__global__ void rs_write(const float* __restrict__ points,
                         const float* __restrict__ queries,
                         const float* __restrict__ radii,
                         const int* __restrict__ splits,
                         float* __restrict__ out_idx,
                         float* __restrict__ out_dist, int N, int M) {
    int wid = (int)((blockIdx.x * blockDim.x + threadIdx.x) >> 6);
    int lane = threadIdx.x & 63;
    if (wid >= M) return;
    float qx = queries[3 * wid + 0];
    float qy = queries[3 * wid + 1];
    float qz = queries[3 * wid + 2];
    float r = radii[wid];
    float r2 = __fmul_rn(r, r);
    long long base = splits[wid];
    int cum = 0;
    unsigned long long lanemask = (lane == 63) ? 0xFFFFFFFFFFFFFFFFull >> 1
                                               : ((1ull << lane) - 1ull);
    for (int p0 = 0; p0 < N; p0 += 64) {
        int p = p0 + lane;
        float px = points[3 * p + 0];
        float py = points[3 * p + 1];
        float pz = points[3 * p + 2];
        float d2 = d2_exact(qx, qy, qz, px, py, pz);
        bool pred = (d2 <= r2);
        unsigned long long mask = __ballot(pred);
        if (pred) {
            long long pos = base + cum + __popcll(mask & lanemask);
            out_idx[pos] = (float)p;
            out_dist[pos] = d2;
        }
        cum += __popcll(mask);
    }
}

extern "C" void kernel_launch(void* const* d_in, const int* in_sizes, int n_in,
                              void* d_out, int out_size, void* d_ws, size_t ws_size,
                              hipStream_t stream) {
    const float* points = (const float*)d_in[0];
    const float* queries = (const float*)d_in[1];
    const float* radii = (const float*)d_in[2];
    int N = in_sizes[0] / 3;
    int M = in_sizes[1] / 3;
    long long MN = (long long)M * (long long)N;

    float* out = (float*)d_out;
    float* out_idx = out;
    float* out_splits = out + MN;
    float* out_dist = out + MN + M + 1;

    int* counts = (int*)d_ws;
    int* splits = counts + M;

    int blocks = (M * 64 + 255) / 256;  // 4 waves/block, 1 wave/query

    rs_count<<<blocks, 256, 0, stream>>>(points, queries, radii, counts, N, M);
    rs_scan<<<1, 256, 0, stream>>>(counts, splits, out_splits, M);
    rs_fill<<<2048, 256, 0, stream>>>(out, 0, MN, -1.0f);
    rs_fill<<<2048, 256, 0, stream>>>(out, MN + (long long)M + 1, MN + (long long)M + 1 + MN, 0.0f);
    rs_write<<<blocks, 256, 0, stream>>>(points, queries, radii, splits, out_idx, out_dist, N, M);
}

// Round 3
// 85.109 us; speedup vs baseline: 1.3804x; 1.3804x over previous
//
#include <hip/hip_runtime.h>

// Radius search (L2^2), single segment, M=4096 queries x N=8192 points.
// Out (float32, concat): [0,MN) packed idx (pad -1) | [MN,MN+M+1) row splits |
//                        [MN+M+1, 2MN+M+1) packed d2 (pad 0).
//
// Exact numpy fp32 op order (NO fma):
//   q2=(qx*qx+qy*qy)+qz*qz ; p2=(px*px+py*py)+pz*pz ; qp=(qx*px+qy*py)+qz*pz
//   d2=max((q2+p2)-2*qp, 0) ; mask: d2<=r*r  (max irrelevant for mask, r2>0)

// ---------- prep: pts4=(x,y,z,p2), q4=(x,y,z,q2), r2 ----------
__global__ void rs_prep(const float* __restrict__ pts, const float* __restrict__ qs,
                        const float* __restrict__ rad,
                        float4* __restrict__ pts4, float4* __restrict__ q4,
                        float* __restrict__ r2, int N, int M) {
    int tid = blockIdx.x * blockDim.x + threadIdx.x;
    int nth = gridDim.x * blockDim.x;
    for (int p = tid; p < N; p += nth) {
        float x = pts[3 * p], y = pts[3 * p + 1], z = pts[3 * p + 2];
        float s = __fadd_rn(__fadd_rn(__fmul_rn(x, x), __fmul_rn(y, y)), __fmul_rn(z, z));
        pts4[p] = make_float4(x, y, z, s);
    }
    for (int m = tid; m < M; m += nth) {
        float x = qs[3 * m], y = qs[3 * m + 1], z = qs[3 * m + 2];
        float s = __fadd_rn(__fadd_rn(__fmul_rn(x, x), __fmul_rn(y, y)), __fmul_rn(z, z));
        q4[m] = make_float4(x, y, z, s);
        float r = rad[m];
        r2[m] = __fmul_rn(r, r);
    }
}

// ---------- fused: count blocks (wave/query, optional mask store) + fill blocks ----------
__global__ void rs_main(const float4* __restrict__ pts4, const float4* __restrict__ q4,
                        const float* __restrict__ r2s,
                        int* __restrict__ counts, unsigned long long* __restrict__ masks,
                        int storeMasks,
                        float* __restrict__ out, long long MN, int N, int M,
                        int countBlocks, int fillPerRegion) {
    int bid = blockIdx.x;
    if (bid < countBlocks) {
        int w = (int)((bid * blockDim.x + threadIdx.x) >> 6);  // wave = query
        int lane = threadIdx.x & 63;
        if (w >= M) return;
        float4 q = q4[w];
        float r2 = r2s[w];
        int nw = N >> 6;  // 64-pt chunks
        unsigned long long* mq = masks + (long long)w * nw;
        int cnt = 0;
#pragma unroll 4
        for (int c = 0; c < nw; ++c) {
            float4 P = pts4[(c << 6) + lane];
            float qp = __fadd_rn(__fadd_rn(__fmul_rn(q.x, P.x), __fmul_rn(q.y, P.y)),
                                 __fmul_rn(q.z, P.z));
            float d2 = __fsub_rn(__fadd_rn(q.w, P.w), __fmul_rn(2.0f, qp));
            unsigned long long b = __ballot(d2 <= r2);
            if (storeMasks && lane == 0) mq[c] = b;
            cnt += __popcll(b);
        }
        if (lane == 0) counts[w] = cnt;
    } else {
        int fb = bid - countBlocks;
        long long start;
        float val;
        int fb0;
        if (fb < fillPerRegion) { start = 0; val = -1.0f; fb0 = fb; }
        else { start = MN + (long long)M + 1; val = 0.0f; fb0 = fb - fillPerRegion; }
        long long n = MN;
        float* base = out + start;
        long long head = (long long)(((16u - ((unsigned)(size_t)base & 15u)) & 15u) >> 2);
        if (head > n) head = n;
        long long tid = (long long)fb0 * blockDim.x + threadIdx.x;
        long long nth = (long long)fillPerRegion * blockDim.x;
        for (long long i = tid; i < head; i += nth) base[i] = val;
        long long nv = (n - head) >> 2;
        float4* v = (float4*)(base + head);
        float4 vv = make_float4(val, val, val, val);
        for (long long i = tid; i < nv; i += nth) v[i] = vv;
        for (long long i = head + (nv << 2) + tid; i < n; i += nth) base[i] = val;
    }
}

// ---------- scan: exclusive prefix of counts -> splits (int ws + float out) ----------
__global__ void rs_scan(const int* __restrict__ counts, int* __restrict__ splits_i,
                        float* __restrict__ splits_f, int M) {
    __shared__ int lds[256];
    int t = threadIdx.x;
    int per = M >> 8;  // 16 for M=4096
    int local[16];
    int sum = 0;
#pragma unroll
    for (int i = 0; i < 16; ++i) {
        int c = (i < per) ? counts[t * per + i] : 0;
        local[i] = sum;
        sum += c;
    }
    lds[t] = sum;
    __syncthreads();
    for (int off = 1; off < 256; off <<= 1) {
        int add = (t >= off) ? lds[t - off] : 0;
        __syncthreads();
        lds[t] += add;
        __syncthreads();
    }
    int excl = (t == 0) ? 0 : lds[t - 1];
#pragma unroll
    for (int i = 0; i < 16; ++i) {
        if (i < per) {
            int v = excl + local[i];
            splits_i[t * per + i] = v;
            splits_f[t * per + i] = (float)v;
        }
    }
    if (t == 255) {
        splits_i[M] = excl + sum;
        splits_f[M] = (float)(excl + sum);
    }
}

// ---------- write (mask path): wave/query, masks -> packed idx+dist ----------
__global__ void rs_write_masks(const float4* __restrict__ pts4, const float4* __restrict__ q4,
                               const unsigned long long* __restrict__ masks,
                               const int* __restrict__ splits,
                               float* __restrict__ out_idx, float* __restrict__ out_dist,
                               int N, int M) {
    int w = (int)((blockIdx.x * blockDim.x + threadIdx.x) >> 6);
    int lane = threadIdx.x & 63;
    if (w >= M) return;
    int nw = N >> 6;  // 128 words per query (<=128 supported)
    const unsigned long long* mq = masks + (long long)w * nw;
    unsigned long long w0 = (lane < nw) ? mq[lane] : 0ull;
    unsigned long long w1 = (lane + 64 < nw) ? mq[lane + 64] : 0ull;
    int c0 = __popcll(w0), c1 = __popcll(w1);
    int i0 = c0, i1 = c1;
    for (int off = 1; off < 64; off <<= 1) {
        int t0 = __shfl_up(i0, off, 64);
        int t1 = __shfl_up(i1, off, 64);
        if (lane >= off) { i0 += t0; i1 += t1; }
    }
    int total0 = __shfl(i0, 63, 64);
    long long base = splits[w];
    float4 q = q4[w];

    long long o = base + (i0 - c0);
    int pbase = lane << 6;
    unsigned long long mm = w0;
    while (mm) {
        int b = __ffsll((long long)mm) - 1;
        int p = pbase + b;
        float4 P = pts4[p];
        float qp = __fadd_rn(__fadd_rn(__fmul_rn(q.x, P.x), __fmul_rn(q.y, P.y)),
                             __fmul_rn(q.z, P.z));
        float d2 = fmaxf(__fsub_rn(__fadd_rn(q.w, P.w), __fmul_rn(2.0f, qp)), 0.0f);
        out_idx[o] = (float)p;
        out_dist[o] = d2;
        ++o;
        mm &= mm - 1;
    }
    o = base + total0 + (i1 - c1);
    pbase = (lane + 64) << 6;
    mm = w1;
    while (mm) {
        int b = __ffsll((long long)mm) - 1;
        int p = pbase + b;
        float4 P = pts4[p];
        float qp = __fadd_rn(__fadd_rn(__fmul_rn(q.x, P.x), __fmul_rn(q.y, P.y)),
                             __fmul_rn(q.z, P.z));
        float d2 = fmaxf(__fsub_rn(__fadd_rn(q.w, P.w), __fmul_rn(2.0f, qp)), 0.0f);
        out_idx[o] = (float)p;
        out_dist[o] = d2;
        ++o;
        mm &= mm - 1;
    }
}

// ---------- write (fallback): wave/query, recompute + ballot pack ----------
__global__ void rs_write_recompute(const float4* __restrict__ pts4,
                                   const float4* __restrict__ q4,
                                   const float* __restrict__ r2s,
                                   const int* __restrict__ splits,
                                   float* __restrict__ out_idx, float* __restrict__ out_dist,
                                   int N, int M) {
    int w = (int)((blockIdx.x * blockDim.x + threadIdx.x) >> 6);
    int lane = threadIdx.x & 63;
    if (w >= M) return;
    float4 q = q4[w];
    float r2 = r2s[w];
    long long base = splits[w];
    int cum = 0;
    unsigned long long lanemask = (1ull << lane) - 1ull;  // lane<=63 safe
    for (int p0 = 0; p0 < N; p0 += 64) {
        int p = p0 + lane;
        float4 P = pts4[p];
        float qp = __fadd_rn(__fadd_rn(__fmul_rn(q.x, P.x), __fmul_rn(q.y, P.y)),
                             __fmul_rn(q.z, P.z));
        float d2 = __fsub_rn(__fadd_rn(q.w, P.w), __fmul_rn(2.0f, qp));
        bool pred = (d2 <= r2);
        unsigned long long mask = __ballot(pred);
        if (pred) {
            long long pos = base + cum + __popcll(mask & lanemask);
            out_idx[pos] = (float)p;
            out_dist[pos] = fmaxf(d2, 0.0f);
        }
        cum += __popcll(mask);
    }
}

extern "C" void kernel_launch(void* const* d_in, const int* in_sizes, int n_in,
                              void* d_out, int out_size, void* d_ws, size_t ws_size,
                              hipStream_t stream) {
    const float* points = (const float*)d_in[0];
    const float* queries = (const float*)d_in[1];
    const float* radii = (const float*)d_in[2];
    int N = in_sizes[0] / 3;
    int M = in_sizes[1] / 3;
    long long MN = (long long)M * (long long)N;

    float* out = (float*)d_out;
    float* out_idx = out;
    float* out_splits = out + MN;
    float* out_dist = out + MN + M + 1;

    // Workspace layout via running-offset allocator (256B aligned per region).
    // R2's failure was a hand-summed offset that omitted `counts` -> masks
    // aliased splits. Never hand-sum offsets again.
    char* ws = (char*)d_ws;
    size_t off = 0;
    auto take = [&](size_t bytes) -> size_t {
        size_t o = off;
        off += (bytes + 255) & ~(size_t)255;
        return o;
    };
    size_t o_pts4 = take((size_t)N * 16);
    size_t o_q4 = take((size_t)M * 16);
    size_t o_r2 = take((size_t)M * 4);
    size_t o_counts = take((size_t)M * 4);
    size_t o_splits = take((size_t)(M + 1) * 4);
    size_t o_masks = take((size_t)M * (size_t)(N / 64) * 8);
    bool useMasks = (off <= ws_size);

    float4* pts4 = (float4*)(ws + o_pts4);
    float4* q4 = (float4*)(ws + o_q4);
    float* r2 = (float*)(ws + o_r2);
    int* counts = (int*)(ws + o_counts);
    int* splits = (int*)(ws + o_splits);
    unsigned long long* masks = (unsigned long long*)(ws + o_masks);

    rs_prep<<<32, 256, 0, stream>>>(points, queries, radii, pts4, q4, r2, N, M);

    int countBlocks = (M * 64 + 255) / 256;  // one wave per query
    int fillPerRegion = 512;
    int grid = countBlocks + 2 * fillPerRegion;
    rs_main<<<grid, 256, 0, stream>>>(pts4, q4, r2, counts, masks, useMasks ? 1 : 0, out,
                                      MN, N, M, countBlocks, fillPerRegion);
    rs_scan<<<1, 256, 0, stream>>>(counts, splits, out_splits, M);
    if (useMasks) {
        rs_write_masks<<<(M * 64 + 255) / 256, 256, 0, stream>>>(pts4, q4, masks, splits,
                                                                 out_idx, out_dist, N, M);
    } else {
        rs_write_recompute<<<(M * 64 + 255) / 256, 256, 0, stream>>>(pts4, q4, r2, splits,
                                                                     out_idx, out_dist, N, M);
    }
}